// Round 4
// baseline (906.259 us; speedup 1.0000x reference)
//
#include <hip/hip_runtime.h>

#define TT 2048
#define BB 8
#define DD 1024
#define NN 64
#define CH 32              // timesteps staged per LDS chunk
#define NCH (TT / CH)

__device__ __forceinline__ float sigmoidf_(float x) {
    return 1.0f / (1.0f + __expf(-x));
}

// All-VALU 8-lane reduction (no LDS pipe, no lgkmcnt):
// quad_perm xor1 (0xB1), quad_perm xor2 (0x4E), then row_half_mirror (0x141)
// to combine the two quads of each 8-lane row group.
// dpp_ctrl must be an ICE -> template parameter.
template <int CTRL>
__device__ __forceinline__ float dpp_add(float x) {
    return x + __int_as_float(__builtin_amdgcn_update_dpp(
        0, __float_as_int(x), CTRL, 0xF, 0xF, true));
}
__device__ __forceinline__ float reduce8(float x) {
    x = dpp_add<0xB1>(x);   // quad_perm xor 1
    x = dpp_add<0x4E>(x);   // quad_perm xor 2
    x = dpp_add<0x141>(x);  // row_half_mirror: combine quad pairs
    return x;
}

// async global->LDS, 16 B/lane. LDS dest is wave-uniform base + lane*16.
__device__ __forceinline__ void gll16(const float* g, float* l) {
    __builtin_amdgcn_global_load_lds(
        (const __attribute__((address_space(1))) void*)g,
        (__attribute__((address_space(3))) void*)l, 16, 0, 0);
}

// ---------------------------------------------------------------------------
// Phase 1: projections. C[m,n] = sum_d x[m,d] * W[n,d]
// grid = (M/128, 4), block 128. 128x64 tile, BK=32, 8x8 micro-tile
// (1.0 B LDS-read per FMA vs 2.0 for 4x4 -> lifts the LDS-read-bound ceiling).
// Register-prefetched staging one K-slab ahead.
// ---------------------------------------------------------------------------
__global__ __launch_bounds__(128) void proj_gemm_kernel(
    const float* __restrict__ x,
    const float* __restrict__ W0, const float* __restrict__ W1,
    const float* __restrict__ W2, const float* __restrict__ W3,
    const float* __restrict__ b_alpha,
    float* __restrict__ O0, float* __restrict__ O1,
    float* __restrict__ O2, float* __restrict__ O3)
{
    const int mat = blockIdx.y;
    const float* __restrict__ W = (mat == 0) ? W0 : (mat == 1) ? W1 : (mat == 2) ? W2 : W3;
    float* __restrict__ C       = (mat == 0) ? O0 : (mat == 1) ? O1 : (mat == 2) ? O2 : O3;

    const int m0  = blockIdx.x * 128;
    const int tid = threadIdx.x;
    const int tx  = tid & 7;    // col group: n = tx*8 .. +8
    const int ty  = tid >> 3;   // row group: m = m0 + ty*8 .. +8

    __shared__ float xs[32][132];   // [kk][row], pad 132 (16B-aligned rows)
    __shared__ float ws[32][68];    // [kk][col]

    float acc[8][8] = {};

    const int r  = tid >> 3;        // 0..15
    const int c4 = (tid & 7) * 4;   // 0..28

    float4 px[8], pw[4];
    #pragma unroll
    for (int j = 0; j < 8; j++)
        px[j] = *(const float4*)&x[(size_t)(m0 + r + 16 * j) * DD + c4];
    #pragma unroll
    for (int j = 0; j < 4; j++)
        pw[j] = *(const float4*)&W[(size_t)(r + 16 * j) * DD + c4];

    for (int k0 = 0; k0 < DD; k0 += 32) {
        #pragma unroll
        for (int j = 0; j < 8; j++) {
            const int row = r + 16 * j;
            xs[c4 + 0][row] = px[j].x;
            xs[c4 + 1][row] = px[j].y;
            xs[c4 + 2][row] = px[j].z;
            xs[c4 + 3][row] = px[j].w;
        }
        #pragma unroll
        for (int j = 0; j < 4; j++) {
            const int row = r + 16 * j;
            ws[c4 + 0][row] = pw[j].x;
            ws[c4 + 1][row] = pw[j].y;
            ws[c4 + 2][row] = pw[j].z;
            ws[c4 + 3][row] = pw[j].w;
        }
        if (k0 + 32 < DD) {
            #pragma unroll
            for (int j = 0; j < 8; j++)
                px[j] = *(const float4*)&x[(size_t)(m0 + r + 16 * j) * DD + k0 + 32 + c4];
            #pragma unroll
            for (int j = 0; j < 4; j++)
                pw[j] = *(const float4*)&W[(size_t)(r + 16 * j) * DD + k0 + 32 + c4];
        }
        __syncthreads();

        #pragma unroll
        for (int kk = 0; kk < 32; kk++) {
            float4 a0 = *(const float4*)&xs[kk][ty * 8];
            float4 a1 = *(const float4*)&xs[kk][ty * 8 + 4];
            float4 b0 = *(const float4*)&ws[kk][tx * 8];
            float4 b1 = *(const float4*)&ws[kk][tx * 8 + 4];
            float a[8] = {a0.x, a0.y, a0.z, a0.w, a1.x, a1.y, a1.z, a1.w};
            float e[8] = {b0.x, b0.y, b0.z, b0.w, b1.x, b1.y, b1.z, b1.w};
            #pragma unroll
            for (int i = 0; i < 8; i++)
                #pragma unroll
                for (int j = 0; j < 8; j++)
                    acc[i][j] = fmaf(a[i], e[j], acc[i][j]);
        }
        __syncthreads();
    }

    if (mat == 3) {
        #pragma unroll
        for (int j = 0; j < 8; j++) {
            const float ba = b_alpha[tx * 8 + j];
            #pragma unroll
            for (int i = 0; i < 8; i++)
                acc[i][j] = sigmoidf_(acc[i][j] + ba);
        }
    }

    #pragma unroll
    for (int i = 0; i < 8; i++) {
        float* cp = &C[(size_t)(m0 + ty * 8 + i) * NN + tx * 8];
        *(float4*)cp       = make_float4(acc[i][0], acc[i][1], acc[i][2], acc[i][3]);
        *(float4*)(cp + 4) = make_float4(acc[i][4], acc[i][5], acc[i][6], acc[i][7]);
    }
}

// ---------------------------------------------------------------------------
// Phase 2: scan. grid = B, block 512 (8 waves -> 2 waves/SIMD for latency
// hiding). Wave owns 8 rows; 8 lanes/row, 8 state elems/lane.
// k/q/v/alpha LDS-staged 32 steps at a time (double-buffered, global_load_lds
// issued a full chunk ahead). All-DPP row reductions; no syncs inside chunks.
// ---------------------------------------------------------------------------
__global__ __launch_bounds__(512) void scan_kernel(
    const float* __restrict__ k_all, const float* __restrict__ v_all,
    const float* __restrict__ q_all, const float* __restrict__ a_all,
    const float* __restrict__ S0,
    const float* __restrict__ d_g, const float* __restrict__ b_g,
    float* __restrict__ out, float* __restrict__ S_final)
{
    const int b    = blockIdx.x;
    const int tid  = threadIdx.x;
    const int lane = tid & 63;
    const int wave = tid >> 6;                 // 0..7
    const int row  = wave * 8 + (lane >> 3);   // 0..63
    const int cs   = (lane & 7) * 8;           // col start: 0,8,..,56

    __shared__ float ks[2][CH * NN];
    __shared__ float qs[2][CH * NN];
    __shared__ float vs[2][CH * NN];
    __shared__ float as_[2][CH * NN];          // 64 KB total

    float S[8];
    {
        float4 s0v = *(const float4*)&S0[((size_t)b * NN + row) * NN + cs];
        float4 s1v = *(const float4*)&S0[((size_t)b * NN + row) * NN + cs + 4];
        S[0] = s0v.x; S[1] = s0v.y; S[2] = s0v.z; S[3] = s0v.w;
        S[4] = s1v.x; S[5] = s1v.y; S[6] = s1v.z; S[7] = s1v.w;
    }
    const float dg = d_g[row];
    const float bg = b_g[row];

    const int stride = BB * NN;

    // wave w stages steps [w*4, w*4+4): one gll16 per array per wave
    // (64 lanes x 16B = 1KB = 4 steps x 256B).
    const int t_lane = lane >> 4;        // 0..3: step within the group
    const int f_lane = (lane & 15) * 4;  // 0..60: float4 column

    auto stage = [&](int chunk, int dbuf) {
        const int s0 = wave * 4;
        const size_t t = (size_t)chunk * CH + s0 + t_lane;
        const size_t goff = (t * BB + b) * NN + f_lane;
        const int loff = s0 * NN;
        gll16(k_all + goff, &ks[dbuf][loff]);
        gll16(q_all + goff, &qs[dbuf][loff]);
        gll16(v_all + goff, &vs[dbuf][loff]);
        gll16(a_all + goff, &as_[dbuf][loff]);
    };

    stage(0, 0);

    float* op = out + b * NN + row;

    for (int c = 0; c < NCH; ++c) {
        const int cb = c & 1;
        __syncthreads();                 // chunk c staged; buf cb^1 free
        if (c + 1 < NCH) stage(c + 1, cb ^ 1);

        const float* kb = ks[cb];
        const float* qb = qs[cb];
        const float* vb = vs[cb];
        const float* ab = as_[cb];

        float4 kc4[2], qc4[2];
        kc4[0] = *(const float4*)&kb[cs];
        kc4[1] = *(const float4*)&kb[cs + 4];
        qc4[0] = *(const float4*)&qb[cs];
        qc4[1] = *(const float4*)&qb[cs + 4];
        float vc = vb[row];
        float ac = ab[row];

        #pragma unroll 4
        for (int s = 0; s < CH; ++s) {
            // distance-1 LDS prefetch (issued first so lgkm waits never land
            // on this step's critical path; wraps and discards at s=CH-1)
            const int sn = (s + 1) & (CH - 1);
            float4 kn4[2], qn4[2];
            kn4[0] = *(const float4*)&kb[sn * NN + cs];
            kn4[1] = *(const float4*)&kb[sn * NN + cs + 4];
            qn4[0] = *(const float4*)&qb[sn * NN + cs];
            qn4[1] = *(const float4*)&qb[sn * NN + cs + 4];
            const float vn = vb[sn * NN + row];
            const float an = ab[sn * NN + row];

            float kc[8] = {kc4[0].x, kc4[0].y, kc4[0].z, kc4[0].w,
                           kc4[1].x, kc4[1].y, kc4[1].z, kc4[1].w};
            float qc[8] = {qc4[0].x, qc4[0].y, qc4[0].z, qc4[0].w,
                           qc4[1].x, qc4[1].y, qc4[1].z, qc4[1].w};

            // retrieved = (S @ k)[row]
            float r0 = fmaf(S[0], kc[0], 0.f);
            float r1 = fmaf(S[1], kc[1], 0.f);
            float r2 = fmaf(S[2], kc[2], 0.f);
            float r3 = fmaf(S[3], kc[3], 0.f);
            r0 = fmaf(S[4], kc[4], r0);
            r1 = fmaf(S[5], kc[5], r1);
            r2 = fmaf(S[6], kc[6], r2);
            r3 = fmaf(S[7], kc[7], r3);
            float rv = reduce8((r0 + r1) + (r2 + r3));

            const float g    = sigmoidf_(fmaf(dg, rv, bg));
            const float coef = (1.0f - ac) * (vc * g);

            // S update + out = (S_new @ q)[row]
            float o0 = 0.f, o1 = 0.f, o2 = 0.f, o3 = 0.f;
            #pragma unroll
            for (int e = 0; e < 8; e += 4) {
                S[e]     = fmaf(ac, S[e],     coef * kc[e]);
                S[e + 1] = fmaf(ac, S[e + 1], coef * kc[e + 1]);
                S[e + 2] = fmaf(ac, S[e + 2], coef * kc[e + 2]);
                S[e + 3] = fmaf(ac, S[e + 3], coef * kc[e + 3]);
                o0 = fmaf(S[e],     qc[e],     o0);
                o1 = fmaf(S[e + 1], qc[e + 1], o1);
                o2 = fmaf(S[e + 2], qc[e + 2], o2);
                o3 = fmaf(S[e + 3], qc[e + 3], o3);
            }
            float ov = reduce8((o0 + o1) + (o2 + o3));

            const float y = ov * ov * sigmoidf_(ov);  // out * silu(out)
            if ((lane & 7) == 0) *op = y;
            op += stride;

            kc4[0] = kn4[0]; kc4[1] = kn4[1];
            qc4[0] = qn4[0]; qc4[1] = qn4[1];
            vc = vn; ac = an;
        }
    }

    {
        float* sp = &S_final[((size_t)b * NN + row) * NN + cs];
        *(float4*)sp       = make_float4(S[0], S[1], S[2], S[3]);
        *(float4*)(sp + 4) = make_float4(S[4], S[5], S[6], S[7]);
    }
}

// ---------------------------------------------------------------------------
extern "C" void kernel_launch(void* const* d_in, const int* in_sizes, int n_in,
                              void* d_out, int out_size, void* d_ws, size_t ws_size,
                              hipStream_t stream) {
    const float* x       = (const float*)d_in[0];
    const float* S0      = (const float*)d_in[1];
    const float* W_k     = (const float*)d_in[2];
    const float* W_v     = (const float*)d_in[3];
    const float* W_q     = (const float*)d_in[4];
    const float* W_alpha = (const float*)d_in[5];
    const float* b_alpha = (const float*)d_in[6];
    const float* d_g     = (const float*)d_in[7];
    const float* b_g     = (const float*)d_in[8];
    float* out = (float*)d_out;

    const size_t arr = (size_t)TT * BB * NN;
    float* ws    = (float*)d_ws;
    float* k_all = ws;
    float* v_all = ws + arr;
    float* q_all = ws + 2 * arr;
    float* a_all = ws + 3 * arr;

    proj_gemm_kernel<<<dim3(TT * BB / 128, 4), 128, 0, stream>>>(
        x, W_k, W_v, W_q, W_alpha, b_alpha, k_all, v_all, q_all, a_all);

    scan_kernel<<<dim3(BB), 512, 0, stream>>>(
        k_all, v_all, q_all, a_all, S0, d_g, b_g,
        out, out + (size_t)TT * BB * NN);
}

// Round 5
// 596.339 us; speedup vs baseline: 1.5197x; 1.5197x over previous
//
#include <hip/hip_runtime.h>

#define TT 2048
#define BB 8
#define DD 1024
#define NN 64
#define CH 32              // timesteps staged per LDS chunk
#define NCH (TT / CH)

__device__ __forceinline__ float sigmoidf_(float x) {
    return 1.0f / (1.0f + __expf(-x));
}

// All-VALU 16-lane reduction via DPP (no LDS pipe, no lgkmcnt).
// After xor1+xor2 all quad members are equal, so row_half_mirror acts as
// xor4 and row_mirror as xor8. All ops confined to the 16-lane DPP row.
template <int CTRL>
__device__ __forceinline__ float dpp_add(float x) {
    return x + __int_as_float(__builtin_amdgcn_update_dpp(
        0, __float_as_int(x), CTRL, 0xF, 0xF, true));
}
__device__ __forceinline__ float reduce16(float x) {
    x = dpp_add<0xB1>(x);   // quad_perm xor 1
    x = dpp_add<0x4E>(x);   // quad_perm xor 2
    x = dpp_add<0x141>(x);  // row_half_mirror (== xor 4 here)
    x = dpp_add<0x140>(x);  // row_mirror      (== xor 8 here)
    return x;
}

// async global->LDS, 16 B/lane. Global side may be per-lane addressed; the
// LDS destination is wave-uniform base + lane*16.
__device__ __forceinline__ void gll16(const float* g, float* l) {
    __builtin_amdgcn_global_load_lds(
        (const __attribute__((address_space(1))) void*)g,
        (__attribute__((address_space(3))) void*)l, 16, 0, 0);
}

// ---------------------------------------------------------------------------
// Phase 1: projections. C[m,n] = sum_d x[m,d] * W[n,d]
// grid = (M/128, 4), block 256. 128x64 tile, BK=32, 8x4 micro-tile.
// acc=32 + prefetch=24 VGPRs leaves the scheduler room to pipeline ds_reads.
// ---------------------------------------------------------------------------
__global__ __launch_bounds__(256) void proj_gemm_kernel(
    const float* __restrict__ x,
    const float* __restrict__ W0, const float* __restrict__ W1,
    const float* __restrict__ W2, const float* __restrict__ W3,
    const float* __restrict__ b_alpha,
    float* __restrict__ O0, float* __restrict__ O1,
    float* __restrict__ O2, float* __restrict__ O3)
{
    const int mat = blockIdx.y;
    const float* __restrict__ W = (mat == 0) ? W0 : (mat == 1) ? W1 : (mat == 2) ? W2 : W3;
    float* __restrict__ C       = (mat == 0) ? O0 : (mat == 1) ? O1 : (mat == 2) ? O2 : O3;

    const int m0  = blockIdx.x * 128;
    const int tid = threadIdx.x;
    const int tx  = tid & 15;   // col group: n = tx*4 .. +4
    const int ty  = tid >> 4;   // row group: m = m0 + ty*8 .. +8

    __shared__ float xs[32][132];   // [kk][row]
    __shared__ float ws[32][68];    // [kk][col]

    float acc[8][4] = {};

    const int r  = tid >> 3;        // 0..31
    const int c4 = (tid & 7) * 4;   // 0..28

    float4 px[4], pw[2];
    #pragma unroll
    for (int j = 0; j < 4; j++)
        px[j] = *(const float4*)&x[(size_t)(m0 + r + 32 * j) * DD + c4];
    #pragma unroll
    for (int j = 0; j < 2; j++)
        pw[j] = *(const float4*)&W[(size_t)(r + 32 * j) * DD + c4];

    for (int k0 = 0; k0 < DD; k0 += 32) {
        #pragma unroll
        for (int j = 0; j < 4; j++) {
            const int row = r + 32 * j;
            xs[c4 + 0][row] = px[j].x;
            xs[c4 + 1][row] = px[j].y;
            xs[c4 + 2][row] = px[j].z;
            xs[c4 + 3][row] = px[j].w;
        }
        #pragma unroll
        for (int j = 0; j < 2; j++) {
            const int row = r + 32 * j;
            ws[c4 + 0][row] = pw[j].x;
            ws[c4 + 1][row] = pw[j].y;
            ws[c4 + 2][row] = pw[j].z;
            ws[c4 + 3][row] = pw[j].w;
        }
        if (k0 + 32 < DD) {
            #pragma unroll
            for (int j = 0; j < 4; j++)
                px[j] = *(const float4*)&x[(size_t)(m0 + r + 32 * j) * DD + k0 + 32 + c4];
            #pragma unroll
            for (int j = 0; j < 2; j++)
                pw[j] = *(const float4*)&W[(size_t)(r + 32 * j) * DD + k0 + 32 + c4];
        }
        __syncthreads();

        #pragma unroll
        for (int kk = 0; kk < 32; kk++) {
            float4 a0 = *(const float4*)&xs[kk][ty * 8];
            float4 a1 = *(const float4*)&xs[kk][ty * 8 + 4];
            float4 bv = *(const float4*)&ws[kk][tx * 4];
            float a[8] = {a0.x, a0.y, a0.z, a0.w, a1.x, a1.y, a1.z, a1.w};
            float e[4] = {bv.x, bv.y, bv.z, bv.w};
            #pragma unroll
            for (int i = 0; i < 8; i++)
                #pragma unroll
                for (int j = 0; j < 4; j++)
                    acc[i][j] = fmaf(a[i], e[j], acc[i][j]);
        }
        __syncthreads();
    }

    if (mat == 3) {
        #pragma unroll
        for (int j = 0; j < 4; j++) {
            const float ba = b_alpha[tx * 4 + j];
            #pragma unroll
            for (int i = 0; i < 8; i++)
                acc[i][j] = sigmoidf_(acc[i][j] + ba);
        }
    }

    #pragma unroll
    for (int i = 0; i < 8; i++) {
        *(float4*)&C[(size_t)(m0 + ty * 8 + i) * NN + tx * 4] =
            make_float4(acc[i][0], acc[i][1], acc[i][2], acc[i][3]);
    }
}

// ---------------------------------------------------------------------------
// Phase 2: scan — ROW-PARALLEL. The recurrence decomposes per state-row i:
// retrieved[i] = S[i,:]·k ; g[i]=sigma(dg[i]*retrieved[i]+bg[i]);
// S[i,:] = a[i]*S[i,:] + (1-a[i])*v[i]*g[i]*k ; out[i] = S[i,:]·q.
// No cross-row coupling -> split 8 batches x 64 rows over 64 blocks.
// grid = (B, 8 octets), block 128 (2 waves; 4 rows/wave; 16 lanes/row,
// 4 state elems/lane). All-DPP 16-lane reductions. k/q/v/alpha LDS-staged
// 32 steps at a time, double-buffered via global_load_lds.
// ---------------------------------------------------------------------------
__global__ __launch_bounds__(128) void scan_kernel(
    const float* __restrict__ k_all, const float* __restrict__ v_all,
    const float* __restrict__ q_all, const float* __restrict__ a_all,
    const float* __restrict__ S0,
    const float* __restrict__ d_g, const float* __restrict__ b_g,
    float* __restrict__ out, float* __restrict__ S_final)
{
    const int b    = blockIdx.x;
    const int oct  = blockIdx.y;               // row octet: rows [oct*8, +8)
    const int r0   = oct * 8;
    const int tid  = threadIdx.x;
    const int lane = tid & 63;
    const int wave = tid >> 6;                 // 0..1
    const int rloc = wave * 4 + (lane >> 4);   // 0..7 (row within octet)
    const int row  = r0 + rloc;                // global state row
    const int cs   = (lane & 15) * 4;          // col start: 0,4,..,60

    __shared__ float ks[2][CH * NN];           // full 64-wide k rows
    __shared__ float qs[2][CH * NN];
    __shared__ float vs[2][CH * 8];            // 8-row slices
    __shared__ float as_[2][CH * 8];           // ~34 KB total

    float S[4];
    {
        float4 s0v = *(const float4*)&S0[((size_t)b * NN + row) * NN + cs];
        S[0] = s0v.x; S[1] = s0v.y; S[2] = s0v.z; S[3] = s0v.w;
    }
    const float dg = d_g[row];
    const float bg = b_g[row];

    const int stride = BB * NN;

    // k/q staging: wave w covers steps [w*16, w*16+16), one gll16 = 4 steps
    // (64 lanes x 16B = 1KB = 4 rows x 256B).
    const int t_lane = lane >> 4;        // 0..3
    const int f_lane = (lane & 15) * 4;  // 0..60
    // v/a staging: one gll16 covers the whole 32-step x 8-row slice:
    // lane l -> step l>>1, rows r0 + (l&1)*4 .. +4.
    const int vs_step = lane >> 1;       // 0..31
    const int vs_half = (lane & 1) * 4;  // 0 or 4

    auto stage = [&](int chunk, int dbuf) {
        #pragma unroll
        for (int j = 0; j < 4; ++j) {
            const int s0 = wave * 16 + j * 4;
            const size_t t = (size_t)chunk * CH + s0 + t_lane;
            const size_t goff = (t * BB + b) * NN + f_lane;
            gll16(k_all + goff, &ks[dbuf][s0 * NN]);
            gll16(q_all + goff, &qs[dbuf][s0 * NN]);
        }
        const size_t tv = (size_t)chunk * CH + vs_step;
        const size_t voff = (tv * BB + b) * NN + r0 + vs_half;
        if (wave == 0) gll16(v_all + voff, &vs[dbuf][0]);
        else           gll16(a_all + voff, &as_[dbuf][0]);
    };

    stage(0, 0);

    float* op = out + b * NN + row;

    for (int c = 0; c < NCH; ++c) {
        const int cb = c & 1;
        __syncthreads();                 // chunk c staged; buf cb^1 free
        if (c + 1 < NCH) stage(c + 1, cb ^ 1);

        const float* kb = ks[cb];
        const float* qb = qs[cb];
        const float* vb = vs[cb];
        const float* ab = as_[cb];

        float4 kc4 = *(const float4*)&kb[cs];
        float4 qc4 = *(const float4*)&qb[cs];
        float vc = vb[rloc];
        float ac = ab[rloc];

        #pragma unroll 4
        for (int s = 0; s < CH; ++s) {
            // distance-1 LDS prefetch (wraps and discards at s=CH-1)
            const int sn = (s + 1) & (CH - 1);
            float4 kn4 = *(const float4*)&kb[sn * NN + cs];
            float4 qn4 = *(const float4*)&qb[sn * NN + cs];
            const float vn = vb[sn * 8 + rloc];
            const float an = ab[sn * 8 + rloc];

            const float kc[4] = {kc4.x, kc4.y, kc4.z, kc4.w};
            const float qc[4] = {qc4.x, qc4.y, qc4.z, qc4.w};

            // retrieved = S[row,:]·k
            float rA = fmaf(S[0], kc[0], 0.f);
            float rB = fmaf(S[1], kc[1], 0.f);
            rA = fmaf(S[2], kc[2], rA);
            rB = fmaf(S[3], kc[3], rB);
            float rv = reduce16(rA + rB);

            const float g    = sigmoidf_(fmaf(dg, rv, bg));
            const float coef = (1.0f - ac) * (vc * g);

            // S update + out = S_new·q
            float oA = 0.f, oB = 0.f;
            S[0] = fmaf(ac, S[0], coef * kc[0]);
            S[1] = fmaf(ac, S[1], coef * kc[1]);
            S[2] = fmaf(ac, S[2], coef * kc[2]);
            S[3] = fmaf(ac, S[3], coef * kc[3]);
            oA = fmaf(S[0], qc[0], oA);
            oB = fmaf(S[1], qc[1], oB);
            oA = fmaf(S[2], qc[2], oA);
            oB = fmaf(S[3], qc[3], oB);
            float ov = reduce16(oA + oB);

            const float y = ov * ov * sigmoidf_(ov);  // out * silu(out)
            if ((lane & 15) == 0) *op = y;
            op += stride;

            kc4 = kn4; qc4 = qn4; vc = vn; ac = an;
        }
    }

    *(float4*)&S_final[((size_t)b * NN + row) * NN + cs] =
        make_float4(S[0], S[1], S[2], S[3]);
}

// ---------------------------------------------------------------------------
extern "C" void kernel_launch(void* const* d_in, const int* in_sizes, int n_in,
                              void* d_out, int out_size, void* d_ws, size_t ws_size,
                              hipStream_t stream) {
    const float* x       = (const float*)d_in[0];
    const float* S0      = (const float*)d_in[1];
    const float* W_k     = (const float*)d_in[2];
    const float* W_v     = (const float*)d_in[3];
    const float* W_q     = (const float*)d_in[4];
    const float* W_alpha = (const float*)d_in[5];
    const float* b_alpha = (const float*)d_in[6];
    const float* d_g     = (const float*)d_in[7];
    const float* b_g     = (const float*)d_in[8];
    float* out = (float*)d_out;

    const size_t arr = (size_t)TT * BB * NN;
    float* ws    = (float*)d_ws;
    float* k_all = ws;
    float* v_all = ws + arr;
    float* q_all = ws + 2 * arr;
    float* a_all = ws + 3 * arr;

    proj_gemm_kernel<<<dim3(TT * BB / 128, 4), 256, 0, stream>>>(
        x, W_k, W_v, W_q, W_alpha, b_alpha, k_all, v_all, q_all, a_all);

    scan_kernel<<<dim3(BB, 8), 128, 0, stream>>>(
        k_all, v_all, q_all, a_all, S0, d_g, b_g,
        out, out + (size_t)TT * BB * NN);
}

// Round 6
// 535.410 us; speedup vs baseline: 1.6926x; 1.1138x over previous
//
#include <hip/hip_runtime.h>

#define TT 2048
#define BB 8
#define DD 1024
#define NN 64
#define CH 32              // timesteps staged per LDS chunk (scan)
#define NCH (TT / CH)

typedef __attribute__((ext_vector_type(8))) short bfrag;    // 8 bf16 (4 VGPRs)
typedef __attribute__((ext_vector_type(4))) float f32x4;    // MFMA C/D
typedef __attribute__((ext_vector_type(8))) unsigned short ushort8;

__device__ __forceinline__ float sigmoidf_(float x) {
    return 1.0f / (1.0f + __expf(-x));
}

// f32 -> bf16 round-to-nearest-even (values are well-behaved, no NaN path)
__device__ __forceinline__ unsigned short cvt_bf16(float f) {
    unsigned int u = __float_as_uint(f);
    return (unsigned short)((u + 0x7FFF + ((u >> 16) & 1)) >> 16);
}

// All-VALU 16-lane reduction via DPP (no LDS pipe, no lgkmcnt).
template <int CTRL>
__device__ __forceinline__ float dpp_add(float x) {
    return x + __int_as_float(__builtin_amdgcn_update_dpp(
        0, __float_as_int(x), CTRL, 0xF, 0xF, true));
}
__device__ __forceinline__ float reduce16(float x) {
    x = dpp_add<0xB1>(x);   // quad_perm xor 1
    x = dpp_add<0x4E>(x);   // quad_perm xor 2
    x = dpp_add<0x141>(x);  // row_half_mirror (== xor 4 here)
    x = dpp_add<0x140>(x);  // row_mirror      (== xor 8 here)
    return x;
}

// async global->LDS, 16 B/lane (scan staging)
__device__ __forceinline__ void gll16(const float* g, float* l) {
    __builtin_amdgcn_global_load_lds(
        (const __attribute__((address_space(1))) void*)g,
        (__attribute__((address_space(3))) void*)l, 16, 0, 0);
}

// ---------------------------------------------------------------------------
// Phase 1: projections via bf16 MFMA. C[m,n] = sum_d x[m,d]*W[n,d], f32 in,
// f32 out, bf16 inputs to the matrix core (f32 accumulate). Error ~3e-3 in
// the projections -- negligible vs the 29.6 absmax budget (gated recurrence
// with alpha<1 keeps perturbations bounded).
// grid = (4 mats, 128 m-tiles) -- mat fastest so all 4 mats stream the same
// x-tile through L2. block = 256 (4 waves). Tile M=128 x N=64, BK=32.
// Wave w computes rows [w*32, w*32+32) as 2x4 MFMA 16x16 tiles.
// ---------------------------------------------------------------------------
__global__ __launch_bounds__(256) void proj_gemm_kernel(
    const float* __restrict__ x,
    const float* __restrict__ W0, const float* __restrict__ W1,
    const float* __restrict__ W2, const float* __restrict__ W3,
    const float* __restrict__ b_alpha,
    float* __restrict__ O0, float* __restrict__ O1,
    float* __restrict__ O2, float* __restrict__ O3)
{
    const int mat = blockIdx.x;
    const float* __restrict__ W = (mat == 0) ? W0 : (mat == 1) ? W1 : (mat == 2) ? W2 : W3;
    float* __restrict__ C       = (mat == 0) ? O0 : (mat == 1) ? O1 : (mat == 2) ? O2 : O3;

    const int m0   = blockIdx.y * 128;
    const int tid  = threadIdx.x;
    const int lane = tid & 63;
    const int wave = tid >> 6;           // 0..3
    const int ln   = lane & 15;          // MFMA row/col-in-tile index
    const int q8   = (lane >> 4) * 8;    // MFMA k offset (quad*8)

    // +8 pad (80 B rows): frag b128 reads land 2-way max (free)
    __shared__ unsigned short As[128][40];
    __shared__ unsigned short Bs[64][40];

    f32x4 acc[2][4] = {};                // [m-subtile][n-subtile]

    // staging assignment: thread t -> A row t>>1, 16-col segment (t&1)*16.
    // threads <128 additionally stage B row t>>1, segment (t&1)*16.
    const int arow = tid >> 1;
    const int aseg = (tid & 1) * 16;

    float4 pa[4], pb[4];
    {
        const float* ap = &x[(size_t)(m0 + arow) * DD + aseg];
        #pragma unroll
        for (int j = 0; j < 4; j++) pa[j] = *(const float4*)(ap + 4 * j);
        if (tid < 128) {
            const float* bp = &W[(size_t)arow * DD + aseg];
            #pragma unroll
            for (int j = 0; j < 4; j++) pb[j] = *(const float4*)(bp + 4 * j);
        }
    }

    for (int k0 = 0; k0 < DD; k0 += 32) {
        __syncthreads();   // prior iteration's frag reads complete
        {
            unsigned short t16[16];
            const float* pf = (const float*)pa;
            #pragma unroll
            for (int j = 0; j < 16; j++) t16[j] = cvt_bf16(pf[j]);
            *(ushort8*)&As[arow][aseg]     = *(ushort8*)&t16[0];
            *(ushort8*)&As[arow][aseg + 8] = *(ushort8*)&t16[8];
            if (tid < 128) {
                const float* qf = (const float*)pb;
                #pragma unroll
                for (int j = 0; j < 16; j++) t16[j] = cvt_bf16(qf[j]);
                *(ushort8*)&Bs[arow][aseg]     = *(ushort8*)&t16[0];
                *(ushort8*)&Bs[arow][aseg + 8] = *(ushort8*)&t16[8];
            }
        }
        if (k0 + 32 < DD) {
            const float* ap = &x[(size_t)(m0 + arow) * DD + k0 + 32 + aseg];
            #pragma unroll
            for (int j = 0; j < 4; j++) pa[j] = *(const float4*)(ap + 4 * j);
            if (tid < 128) {
                const float* bp = &W[(size_t)arow * DD + k0 + 32 + aseg];
                #pragma unroll
                for (int j = 0; j < 4; j++) pb[j] = *(const float4*)(bp + 4 * j);
            }
        }
        __syncthreads();   // LDS tile visible

        bfrag af[2], bf[4];
        #pragma unroll
        for (int mt = 0; mt < 2; mt++)
            af[mt] = *(const bfrag*)&As[wave * 32 + mt * 16 + ln][q8];
        #pragma unroll
        for (int nt = 0; nt < 4; nt++)
            bf[nt] = *(const bfrag*)&Bs[nt * 16 + ln][q8];
        #pragma unroll
        for (int mt = 0; mt < 2; mt++)
            #pragma unroll
            for (int nt = 0; nt < 4; nt++)
                acc[mt][nt] = __builtin_amdgcn_mfma_f32_16x16x32_bf16(
                    af[mt], bf[nt], acc[mt][nt], 0, 0, 0);
    }

    // epilogue: C/D layout col=lane&15, row=(lane>>4)*4+reg (per 16x16 tile)
    #pragma unroll
    for (int nt = 0; nt < 4; nt++) {
        const int col = nt * 16 + ln;
        const float ba = (mat == 3) ? b_alpha[col] : 0.0f;
        #pragma unroll
        for (int mt = 0; mt < 2; mt++) {
            #pragma unroll
            for (int r = 0; r < 4; r++) {
                const int row = m0 + wave * 32 + mt * 16 + (lane >> 4) * 4 + r;
                float v = acc[mt][nt][r];
                if (mat == 3) v = sigmoidf_(v + ba);
                C[(size_t)row * NN + col] = v;
            }
        }
    }
}

// ---------------------------------------------------------------------------
// Phase 2: scan -- ROW-PARALLEL (unchanged from R5, known 398 us).
// grid = (B, 8 octets), block 128 (2 waves; 4 rows/wave; 16 lanes/row,
// 4 state elems/lane). All-DPP 16-lane reductions. k/q/v/alpha LDS-staged
// 32 steps at a time, double-buffered via global_load_lds.
// ---------------------------------------------------------------------------
__global__ __launch_bounds__(128) void scan_kernel(
    const float* __restrict__ k_all, const float* __restrict__ v_all,
    const float* __restrict__ q_all, const float* __restrict__ a_all,
    const float* __restrict__ S0,
    const float* __restrict__ d_g, const float* __restrict__ b_g,
    float* __restrict__ out, float* __restrict__ S_final)
{
    const int b    = blockIdx.x;
    const int oct  = blockIdx.y;               // rows [oct*8, +8)
    const int r0   = oct * 8;
    const int tid  = threadIdx.x;
    const int lane = tid & 63;
    const int wave = tid >> 6;                 // 0..1
    const int rloc = wave * 4 + (lane >> 4);   // 0..7
    const int row  = r0 + rloc;
    const int cs   = (lane & 15) * 4;

    __shared__ float ks[2][CH * NN];
    __shared__ float qs[2][CH * NN];
    __shared__ float vs[2][CH * 8];
    __shared__ float as_[2][CH * 8];

    float S[4];
    {
        float4 s0v = *(const float4*)&S0[((size_t)b * NN + row) * NN + cs];
        S[0] = s0v.x; S[1] = s0v.y; S[2] = s0v.z; S[3] = s0v.w;
    }
    const float dg = d_g[row];
    const float bg = b_g[row];

    const int stride = BB * NN;

    const int t_lane = lane >> 4;        // 0..3
    const int f_lane = (lane & 15) * 4;  // 0..60
    const int vs_step = lane >> 1;       // 0..31
    const int vs_half = (lane & 1) * 4;  // 0 or 4

    auto stage = [&](int chunk, int dbuf) {
        #pragma unroll
        for (int j = 0; j < 4; ++j) {
            const int s0 = wave * 16 + j * 4;
            const size_t t = (size_t)chunk * CH + s0 + t_lane;
            const size_t goff = (t * BB + b) * NN + f_lane;
            gll16(k_all + goff, &ks[dbuf][s0 * NN]);
            gll16(q_all + goff, &qs[dbuf][s0 * NN]);
        }
        const size_t tv = (size_t)chunk * CH + vs_step;
        const size_t voff = (tv * BB + b) * NN + r0 + vs_half;
        if (wave == 0) gll16(v_all + voff, &vs[dbuf][0]);
        else           gll16(a_all + voff, &as_[dbuf][0]);
    };

    stage(0, 0);

    float* op = out + b * NN + row;

    for (int c = 0; c < NCH; ++c) {
        const int cb = c & 1;
        __syncthreads();
        if (c + 1 < NCH) stage(c + 1, cb ^ 1);

        const float* kb = ks[cb];
        const float* qb = qs[cb];
        const float* vb = vs[cb];
        const float* ab = as_[cb];

        float4 kc4 = *(const float4*)&kb[cs];
        float4 qc4 = *(const float4*)&qb[cs];
        float vc = vb[rloc];
        float ac = ab[rloc];

        #pragma unroll 4
        for (int s = 0; s < CH; ++s) {
            const int sn = (s + 1) & (CH - 1);
            float4 kn4 = *(const float4*)&kb[sn * NN + cs];
            float4 qn4 = *(const float4*)&qb[sn * NN + cs];
            const float vn = vb[sn * 8 + rloc];
            const float an = ab[sn * 8 + rloc];

            const float kc[4] = {kc4.x, kc4.y, kc4.z, kc4.w};
            const float qc[4] = {qc4.x, qc4.y, qc4.z, qc4.w};

            float rA = fmaf(S[0], kc[0], 0.f);
            float rB = fmaf(S[1], kc[1], 0.f);
            rA = fmaf(S[2], kc[2], rA);
            rB = fmaf(S[3], kc[3], rB);
            float rv = reduce16(rA + rB);

            const float g    = sigmoidf_(fmaf(dg, rv, bg));
            const float coef = (1.0f - ac) * (vc * g);

            float oA = 0.f, oB = 0.f;
            S[0] = fmaf(ac, S[0], coef * kc[0]);
            S[1] = fmaf(ac, S[1], coef * kc[1]);
            S[2] = fmaf(ac, S[2], coef * kc[2]);
            S[3] = fmaf(ac, S[3], coef * kc[3]);
            oA = fmaf(S[0], qc[0], oA);
            oB = fmaf(S[1], qc[1], oB);
            oA = fmaf(S[2], qc[2], oA);
            oB = fmaf(S[3], qc[3], oB);
            float ov = reduce16(oA + oB);

            const float y = ov * ov * sigmoidf_(ov);
            if ((lane & 15) == 0) *op = y;
            op += stride;

            kc4 = kn4; qc4 = qn4; vc = vn; ac = an;
        }
    }

    *(float4*)&S_final[((size_t)b * NN + row) * NN + cs] =
        make_float4(S[0], S[1], S[2], S[3]);
}

// ---------------------------------------------------------------------------
extern "C" void kernel_launch(void* const* d_in, const int* in_sizes, int n_in,
                              void* d_out, int out_size, void* d_ws, size_t ws_size,
                              hipStream_t stream) {
    const float* x       = (const float*)d_in[0];
    const float* S0      = (const float*)d_in[1];
    const float* W_k     = (const float*)d_in[2];
    const float* W_v     = (const float*)d_in[3];
    const float* W_q     = (const float*)d_in[4];
    const float* W_alpha = (const float*)d_in[5];
    const float* b_alpha = (const float*)d_in[6];
    const float* d_g     = (const float*)d_in[7];
    const float* b_g     = (const float*)d_in[8];
    float* out = (float*)d_out;

    const size_t arr = (size_t)TT * BB * NN;
    float* ws    = (float*)d_ws;
    float* k_all = ws;
    float* v_all = ws + arr;
    float* q_all = ws + 2 * arr;
    float* a_all = ws + 3 * arr;

    proj_gemm_kernel<<<dim3(4, TT * BB / 128), 256, 0, stream>>>(
        x, W_k, W_v, W_q, W_alpha, b_alpha, k_all, v_all, q_all, a_all);

    scan_kernel<<<dim3(BB, 8), 128, 0, stream>>>(
        k_all, v_all, q_all, a_all, S0, d_g, b_g,
        out, out + (size_t)TT * BB * NN);
}